// Round 1
// baseline (324.910 us; speedup 1.0000x reference)
//
#include <hip/hip_runtime.h>
#include <hip/hip_bf16.h>

#define ALPHA_ 1.0f
#define BETA_  0.5f
#define GAMMA_ 0.3f
#define EPS_   1e-8f

typedef unsigned short u16;

constexpr int B_ = 32, C_ = 256, F_ = 2048;
constexpr int NTOT = B_ * C_ * F_;          // 16777216
constexpr int N4   = NTOT / 4;              // 4194304
constexpr int NCC  = B_ * C_ * C_;          // 2097152

typedef __bf16 bf16x8 __attribute__((ext_vector_type(8)));
typedef float  f32x4  __attribute__((ext_vector_type(4)));

// round-to-nearest-even float -> bf16 bits (inputs are sin/cos, no NaN/Inf)
__device__ __forceinline__ u16 f2bf(float x) {
    unsigned u = __float_as_uint(x);
    u += 0x7fffu + ((u >> 16) & 1u);
    return (u16)(u >> 16);
}

// ---------------------------------------------------------------------------
// Kernel A: elementwise mag/phase losses + cos/sin(phase_hat) -> bf16 in ws
// ---------------------------------------------------------------------------
__global__ void __launch_bounds__(256)
ew_kernel(const float4* __restrict__ mh, const float4* __restrict__ ph,
          const float4* __restrict__ mt, const float4* __restrict__ pt,
          short4* __restrict__ cb, short4* __restrict__ sb,
          float* __restrict__ accum)
{
    __shared__ float sm[4], sp[4];
    int tid    = blockIdx.x * 256 + threadIdx.x;
    int stride = gridDim.x * 256;
    float msum = 0.f, psum = 0.f;

    for (int i = tid; i < N4; i += stride) {
        float4 a = mh[i], b = mt[i];
        float dx = a.x - b.x, dy = a.y - b.y, dz = a.z - b.z, dw = a.w - b.w;
        msum += dx * dx + dy * dy + dz * dz + dw * dw;

        float4 p = ph[i], q = pt[i];
        psum += 4.f - __cosf(p.x - q.x) - __cosf(p.y - q.y)
                    - __cosf(p.z - q.z) - __cosf(p.w - q.w);

        float sx, cx, sy, cy, sz, cz, sw, cw;
        __sincosf(p.x, &sx, &cx);
        __sincosf(p.y, &sy, &cy);
        __sincosf(p.z, &sz, &cz);
        __sincosf(p.w, &sw, &cw);
        cb[i] = make_short4((short)f2bf(cx), (short)f2bf(cy),
                            (short)f2bf(cz), (short)f2bf(cw));
        sb[i] = make_short4((short)f2bf(sx), (short)f2bf(sy),
                            (short)f2bf(sz), (short)f2bf(sw));
    }

    #pragma unroll
    for (int o = 32; o > 0; o >>= 1) {
        msum += __shfl_down(msum, o, 64);
        psum += __shfl_down(psum, o, 64);
    }
    int lane = threadIdx.x & 63, wv = threadIdx.x >> 6;
    if (lane == 0) { sm[wv] = msum; sp[wv] = psum; }
    __syncthreads();
    if (threadIdx.x == 0) {
        atomicAdd(&accum[0], sm[0] + sm[1] + sm[2] + sm[3]);
        atomicAdd(&accum[1], sp[0] + sp[1] + sp[2] + sp[3]);
    }
}

// ---------------------------------------------------------------------------
// Kernel B: batched MFMA "GEMM" -> pci -> (pci - target)^2 reduce.
// One block = one 64x64 output tile of one batch. 4 waves, each 32x32.
// Per 16x16 tile keep 3 accumulators: (cc+ss), sc, cs; imag = sc - cs.
// ---------------------------------------------------------------------------
#define LDA 40   // 32 + 8 pad (16B) -> conflict-free b128 reads, keeps 16B align

__global__ void __launch_bounds__(256)
pci_kernel(const u16* __restrict__ cb, const u16* __restrict__ sb,
           const float* __restrict__ tgt, float* __restrict__ accum)
{
    __shared__ u16 lac[64 * LDA], las[64 * LDA];
    __shared__ u16 lbc[64 * LDA], lbs[64 * LDA];
    __shared__ float sred[4];

    const int b  = blockIdx.y;
    const int ti = blockIdx.x >> 2, tj = blockIdx.x & 3;
    const int i0 = ti * 64, j0 = tj * 64;

    const int t    = threadIdx.x;
    const int lane = t & 63, wv = t >> 6;
    const int wrow = (wv >> 1) * 32, wcol = (wv & 1) * 32;
    const int m = lane & 15, q = lane >> 4;

    // staging: thread t loads one 16B chunk per array: row=t>>2, k-chunk=t&3
    const int srow = t >> 2;
    const int sk   = (t & 3) << 3;
    const size_t bbase = (size_t)b * (C_ * F_);
    const size_t ga = bbase + (size_t)(i0 + srow) * F_ + sk;
    const size_t gb = bbase + (size_t)(j0 + srow) * F_ + sk;
    const int ldst = srow * LDA + sk;

    f32x4 zero = {0.f, 0.f, 0.f, 0.f};
    f32x4 accR[2][2], accSC[2][2], accCS[2][2];
    #pragma unroll
    for (int a = 0; a < 2; a++)
        #pragma unroll
        for (int c = 0; c < 2; c++) {
            accR[a][c] = zero; accSC[a][c] = zero; accCS[a][c] = zero;
        }

    for (int k0 = 0; k0 < F_; k0 += 32) {
        __syncthreads();
        *(int4*)&lac[ldst] = *(const int4*)&cb[ga + k0];
        *(int4*)&las[ldst] = *(const int4*)&sb[ga + k0];
        *(int4*)&lbc[ldst] = *(const int4*)&cb[gb + k0];
        *(int4*)&lbs[ldst] = *(const int4*)&sb[gb + k0];
        __syncthreads();

        bf16x8 fac[2], fas[2], fbc[2], fbs[2];
        #pragma unroll
        for (int a = 0; a < 2; a++) {
            int r = (wrow + a * 16 + m) * LDA + q * 8;
            fac[a] = *(const bf16x8*)&lac[r];
            fas[a] = *(const bf16x8*)&las[r];
        }
        #pragma unroll
        for (int c = 0; c < 2; c++) {
            int r = (wcol + c * 16 + m) * LDA + q * 8;
            fbc[c] = *(const bf16x8*)&lbc[r];
            fbs[c] = *(const bf16x8*)&lbs[r];
        }

        #pragma unroll
        for (int a = 0; a < 2; a++)
            #pragma unroll
            for (int c = 0; c < 2; c++) {
                accR[a][c]  = __builtin_amdgcn_mfma_f32_16x16x32_bf16(fac[a], fbc[c], accR[a][c], 0, 0, 0);
                accR[a][c]  = __builtin_amdgcn_mfma_f32_16x16x32_bf16(fas[a], fbs[c], accR[a][c], 0, 0, 0);
                accSC[a][c] = __builtin_amdgcn_mfma_f32_16x16x32_bf16(fas[a], fbc[c], accSC[a][c], 0, 0, 0);
                accCS[a][c] = __builtin_amdgcn_mfma_f32_16x16x32_bf16(fac[a], fbs[c], accCS[a][c], 0, 0, 0);
            }
    }

    // epilogue: pci -> squared error vs target, accumulate
    const float inv_f = 1.0f / (float)F_;
    float coh = 0.f;
    const float* tb = tgt + (size_t)b * (C_ * C_);
    #pragma unroll
    for (int a = 0; a < 2; a++)
        #pragma unroll
        for (int c = 0; c < 2; c++) {
            int irow = i0 + wrow + a * 16 + q * 4;   // C/D: row=(lane>>4)*4+reg
            int jcol = j0 + wcol + c * 16 + m;       // C/D: col=lane&15
            #pragma unroll
            for (int r = 0; r < 4; r++) {
                float re = accR[a][c][r] * inv_f;
                float im = (accSC[a][c][r] - accCS[a][c][r]) * inv_f;
                float p  = sqrtf(re * re + im * im + EPS_);
                float d  = p - tb[(irow + r) * C_ + jcol];
                coh += d * d;
            }
        }

    #pragma unroll
    for (int o = 32; o > 0; o >>= 1) coh += __shfl_down(coh, o, 64);
    if (lane == 0) sred[wv] = coh;
    __syncthreads();
    if (t == 0) atomicAdd(&accum[2], sred[0] + sred[1] + sred[2] + sred[3]);
}

// ---------------------------------------------------------------------------
// Kernel C: finalize the 4 scalars
// ---------------------------------------------------------------------------
__global__ void fin_kernel(const float* __restrict__ accum, float* __restrict__ out)
{
    if (threadIdx.x == 0) {
        float mag = accum[0] * (1.0f / (float)NTOT);
        float phs = accum[1] * (1.0f / (float)NTOT);
        float coh = accum[2] * (1.0f / (float)NCC);
        out[0] = ALPHA_ * mag + BETA_ * phs + GAMMA_ * coh;
        out[1] = mag;
        out[2] = phs;
        out[3] = coh;
    }
}

extern "C" void kernel_launch(void* const* d_in, const int* in_sizes, int n_in,
                              void* d_out, int out_size, void* d_ws, size_t ws_size,
                              hipStream_t stream)
{
    // setup_inputs order: mag_hat, phase_hat, mag_target, phase_target, pci_target
    const float* mh  = (const float*)d_in[0];
    const float* ph  = (const float*)d_in[1];
    const float* mt  = (const float*)d_in[2];
    const float* pt  = (const float*)d_in[3];
    const float* tgt = (const float*)d_in[4];
    float* out = (float*)d_out;

    // ws layout: [0..3] float accumulators | cb (N bf16) | sb (N bf16)
    float* accum = (float*)d_ws;
    u16* cb = (u16*)((char*)d_ws + 256);
    u16* sb = cb + (size_t)NTOT;

    hipMemsetAsync(d_ws, 0, 16, stream);

    ew_kernel<<<2048, 256, 0, stream>>>(
        (const float4*)mh, (const float4*)ph, (const float4*)mt, (const float4*)pt,
        (short4*)cb, (short4*)sb, accum);

    dim3 grid(16, 32);
    pci_kernel<<<grid, 256, 0, stream>>>(cb, sb, tgt, accum);

    fin_kernel<<<1, 64, 0, stream>>>(accum, out);
}